// Round 3
// baseline (38119.986 us; speedup 1.0000x reference)
//
#include <hip/hip_runtime.h>

#define TT 512
#define BSZ 64
#define DD 512
#define HH 512
#define NGROUP 4
#define GBLK 64        // blocks per group
#define GBATCH 16      // batches per group
#define NT 1024        // threads per block (16 waves -> 4 waves/SIMD)

struct Params {
    const float* X;
    const float* Wx[4];   // W_xi, W_xf, W_xo, W_xc   [D][H] row-major
    const float* Wh[4];   // W_hi, W_hf, W_ho, W_hc   [H][H] row-major
    const float* bias[4]; // b_i, b_f, b_o, b_c       [H]
    float* Y;             // [B][T][H]
    float* hbuf;          // ws: 2 * B * H floats (double buffer)
    unsigned int* ctr;    // ws: NGROUP counters, 64-uint padded
};

__device__ __forceinline__ float fast_sigmoid(float x) {
    return 1.0f / (1.0f + __expf(-x));
}

__device__ __forceinline__ float fast_tanh(float x) {
    float ax = fabsf(x);
    float e  = __expf(-2.0f * ax);
    float r  = (1.0f - e) / (1.0f + e);
    return copysignf(r, x);
}

// hbuf/ctr are accessed ONLY via cache-bypassing (agent-scope relaxed) ops in
// the main kernel, so the init writes must also be write-through.
__global__ void init_ws(float* hbuf, unsigned int* ctr) {
    int i = blockIdx.x * blockDim.x + threadIdx.x;
    int stride = gridDim.x * blockDim.x;
    for (int k = i; k < 2 * BSZ * HH; k += stride)
        __hip_atomic_store(&hbuf[k], 0.0f, __ATOMIC_RELAXED, __HIP_MEMORY_SCOPE_AGENT);
    if (i < 8 * 64)
        __hip_atomic_store(&ctr[i], 0u, __ATOMIC_RELAXED, __HIP_MEMORY_SCOPE_AGENT);
}

// Persistent LSTM. 256 blocks x 1024 threads. 99.3 KB LDS -> 1 block/CU,
// 16 waves = 4 waves/SIMD.
// R3 change: occupancy was STILL the binding constraint (R2: 2 waves/SIMD,
// VALUBusy 56%, ~4us/step exposed latency). Doubling waves requires K-slice
// 16/thread -> W_x fits in registers (4 float4) -> wx_lds (66 KB) deleted ->
// LDS 99.3 KB keeps 1 block/CU at 16 waves. x-loop also loses 4 ds_read_b32
// per chunk (weights now VGPRs).
// SPILL GUARD: 32 w-floats/thread total; both FMA loops are 4-chunk unrolled
// with sched_barrier(0) after each chunk (<=16 b128 loads in flight). This is
// the exact pattern that compiled to 88 VGPR in R2. __launch_bounds__(1024,4)
// caps at 128 VGPR. If WRITE_SIZE grows vs 135 MB, it spilled.
//
// XCD-pair swizzle: group g -> XCDs {2g,2g+1} (bid%8 round-robin assumption).
// COHERENCE: h exchange is Infinity-Cache-coherent with ZERO fences.
// Producer: relaxed agent store (write-through). __syncthreads drains vmcnt.
// tid0 relaxed fetch_add publish; consumer tid0 relaxed spin, h staged via
// relaxed agent loads (bypass L1/L2, served by IF).
__global__ __launch_bounds__(NT, 4) void lstm_persist(Params p) {
    __shared__ float hs[GBATCH * HH];         // 32 KB: h_{t-1}, 16 batches
    __shared__ float xs[GBATCH * DD];         // 32 KB: x_t, 16 batches
    __shared__ float part[GBATCH * 16 * 33];  // 33.8 KB: partials [bb][spair][33(c)]

    const int bid  = blockIdx.x;
    // XCD-pair swizzle (XCD assumed = bid & 7)
    const int g    = (bid & 7) >> 1;               // group 0..3 -> XCDs {2g,2g+1}
    const int k    = ((bid >> 3) << 1) | (bid & 1); // block-in-group 0..63
    const int tid  = threadIdx.x;
    const int c    = tid & 31;             // col 0..31
    const int s    = tid >> 5;             // K-slice 0..31
    const int gate = c >> 3;
    const int jcol = k * 8 + (c & 7);      // weight-matrix column
    const int b0   = g * GBATCH;
    const int kb   = s * 16;               // K-slice start (16 rows/thread)

    // ---- one-time: W_x and W_h slices into registers (16+16 floats) ----
    const float* WxG = p.Wx[gate];
    const float* WhG = p.Wh[gate];
    float4 wx4[4], wh4[4];
#pragma unroll
    for (int i = 0; i < 4; ++i) {
        int kk = kb + i * 4;
        wx4[i] = make_float4(WxG[(kk + 0) * HH + jcol], WxG[(kk + 1) * HH + jcol],
                             WxG[(kk + 2) * HH + jcol], WxG[(kk + 3) * HH + jcol]);
        wh4[i] = make_float4(WhG[(kk + 0) * HH + jcol], WhG[(kk + 1) * HH + jcol],
                             WhG[(kk + 2) * HH + jcol], WhG[(kk + 3) * HH + jcol]);
    }

    // Cell-update thread state (threads 0..127): (batch bbu, unit jju)
    const int bbu = tid >> 3;              // 0..15 (for tid<128)
    const int jju = tid & 7;
    const int ju  = k * 8 + jju;
    float cst = 0.0f;
    float bI = 0.f, bF = 0.f, bO = 0.f, bC = 0.f;
    if (tid < 128) {
        bI = p.bias[0][ju];
        bF = p.bias[1][ju];
        bO = p.bias[2][ju];
        bC = p.bias[3][ju];
    }

    unsigned int* ctrp = p.ctr + g * 64;
    const float4* xsrc = (const float4*)p.X;
    float4* hs4 = (float4*)hs;
    float4* xs4 = (float4*)xs;

    for (int t = 0; t < TT; ++t) {
        // ---- 1. stage x_t (no cross-block dependency): 2 float4/thread ----
#pragma unroll
        for (int u = 0; u < 2; ++u) {
            int idx = tid + u * NT;            // 0..2047 (float4 index)
            int b   = idx >> 7;                // 0..15
            int dd  = idx & 127;               // float4 within row
            xs4[b * 128 + dd] = xsrc[((size_t)(b0 + b) * TT + t) * 128 + dd];
        }
        __syncthreads();

        // ---- 2. x-projection FMAs, weights from registers.
        //      4 chunks x (16 ds_read_b128 + 64 FMA), sched_barrier bounded ----
        float acc[16];
#pragma unroll
        for (int bb = 0; bb < 16; ++bb) acc[bb] = 0.0f;
#pragma unroll
        for (int i4 = 0; i4 < 4; ++i4) {
            const float4 w = wx4[i4];
            const float4* xp = &xs4[s * 4 + i4];
#pragma unroll
            for (int bb = 0; bb < 16; ++bb) {
                float4 xv = xp[bb * 128];      // half-wave broadcast
                float a = acc[bb];
                a = fmaf(xv.x, w.x, a);
                a = fmaf(xv.y, w.y, a);
                a = fmaf(xv.z, w.z, a);
                a = fmaf(xv.w, w.w, a);
                acc[bb] = a;
            }
            __builtin_amdgcn_sched_barrier(0);
        }

        // ---- 3. wait for h_{t-1}: tid0-only relaxed spin (bypass load reads
        //      the IF directly — no fence, no cache invalidation) ----
        if (tid == 0) {
            const unsigned int need = (unsigned int)(GBLK * t);
            while (__hip_atomic_load(ctrp, __ATOMIC_RELAXED, __HIP_MEMORY_SCOPE_AGENT) < need) {
                __builtin_amdgcn_s_sleep(2);
            }
        }
        __syncthreads();

        // ---- 4. stage h_{t-1}: cache-bypassing (IF-coherent) loads,
        //      register-batched so all 8 loads are in flight at once ----
        {
            const float* hsrc = p.hbuf + (size_t)(t & 1) * BSZ * HH;
            float tmp[8];
#pragma unroll
            for (int u = 0; u < 8; ++u) {
                int idx = tid + u * NT;        // 0..8191
                int b   = idx >> 9;            // 0..15
                int d   = idx & 511;
                tmp[u] = __hip_atomic_load(&hsrc[(size_t)(b0 + b) * HH + d],
                                           __ATOMIC_RELAXED, __HIP_MEMORY_SCOPE_AGENT);
            }
#pragma unroll
            for (int u = 0; u < 8; ++u) {
                int idx = tid + u * NT;
                hs[idx] = tmp[u];
            }
        }
        __syncthreads();

        // ---- 5. recurrent FMAs, weights from registers ----
#pragma unroll
        for (int i4 = 0; i4 < 4; ++i4) {
            const float4 w = wh4[i4];
            const float4* hp = &hs4[s * 4 + i4];
#pragma unroll
            for (int bb = 0; bb < 16; ++bb) {
                float4 hv = hp[bb * 128];      // half-wave broadcast
                float a = acc[bb];
                a = fmaf(hv.x, w.x, a);
                a = fmaf(hv.y, w.y, a);
                a = fmaf(hv.z, w.z, a);
                a = fmaf(hv.w, w.w, a);
                acc[bb] = a;
            }
            __builtin_amdgcn_sched_barrier(0);
        }

        // ---- 6. pair-combine K-slices s and s^1 in-register (same wave:
        //      lanes 0..31 hold s even, 32..63 hold s odd), then write 16
        //      partial slices (stride 33: conflict-free) ----
#pragma unroll
        for (int bb = 0; bb < 16; ++bb)
            acc[bb] += __shfl_xor(acc[bb], 32);
        if ((s & 1) == 0) {
#pragma unroll
            for (int bb = 0; bb < 16; ++bb)
                part[(bb * 16 + (s >> 1)) * 33 + c] = acc[bb];
        }
        __syncthreads();

        // ---- 7. cell update ----
        if (tid < 128) {
            float v0 = bI, v1 = bF, v2 = bO, v3 = bC;
#pragma unroll
            for (int ss = 0; ss < 16; ++ss) {
                const float* pr = &part[(bbu * 16 + ss) * 33];
                v0 += pr[0 * 8 + jju];
                v1 += pr[1 * 8 + jju];
                v2 += pr[2 * 8 + jju];
                v3 += pr[3 * 8 + jju];
            }
            float I  = fast_sigmoid(v0);
            float F  = fast_sigmoid(v1);
            float O  = fast_sigmoid(v2);
            float Cd = fast_tanh(v3);
            cst = fmaf(F, cst, I * Cd);
            float h = O * fast_tanh(cst);
            // write-through to the IF (coherence point)
            __hip_atomic_store(&p.hbuf[(size_t)((t + 1) & 1) * BSZ * HH + (b0 + bbu) * HH + ju],
                               h, __ATOMIC_RELAXED, __HIP_MEMORY_SCOPE_AGENT);
            p.Y[((size_t)(b0 + bbu) * TT + t) * HH + ju] = h;
        }
        __syncthreads();   // drains vmcnt: h stores complete at the IF

        // ---- 8. publish: tid0 RELAXED add (ordering via the vmcnt drain) ----
        if (tid == 0) {
            __hip_atomic_fetch_add(ctrp, 1u, __ATOMIC_RELAXED, __HIP_MEMORY_SCOPE_AGENT);
        }
    }
}

extern "C" void kernel_launch(void* const* d_in, const int* in_sizes, int n_in,
                              void* d_out, int out_size, void* d_ws, size_t ws_size,
                              hipStream_t stream) {
    Params p;
    p.X       = (const float*)d_in[0];
    p.Wx[0]   = (const float*)d_in[1];
    p.Wh[0]   = (const float*)d_in[2];
    p.bias[0] = (const float*)d_in[3];
    p.Wx[1]   = (const float*)d_in[4];
    p.Wh[1]   = (const float*)d_in[5];
    p.bias[1] = (const float*)d_in[6];
    p.Wx[2]   = (const float*)d_in[7];
    p.Wh[2]   = (const float*)d_in[8];
    p.bias[2] = (const float*)d_in[9];
    p.Wx[3]   = (const float*)d_in[10];
    p.Wh[3]   = (const float*)d_in[11];
    p.bias[3] = (const float*)d_in[12];
    p.Y       = (float*)d_out;
    p.hbuf    = (float*)d_ws;
    p.ctr     = (unsigned int*)((char*)d_ws + (size_t)2 * BSZ * HH * sizeof(float));

    // ws is poisoned 0xAA before every timed launch: zero h0 double-buffer + counters
    init_ws<<<64, 256, 0, stream>>>(p.hbuf, p.ctr);

    lstm_persist<<<dim3(256), dim3(NT), 0, stream>>>(p);
}

// Round 4
// 35564.322 us; speedup vs baseline: 1.0719x; 1.0719x over previous
//
#include <hip/hip_runtime.h>

#define TT 512
#define BSZ 64
#define DD 512
#define HH 512
#define NGROUP 4
#define GBLK 64        // blocks per group
#define GBATCH 16      // batches per group
#define NT 1024        // threads per block (16 waves -> 4 waves/SIMD)

struct Params {
    const float* X;
    const float* Wx[4];   // W_xi, W_xf, W_xo, W_xc   [D][H] row-major
    const float* Wh[4];   // W_hi, W_hf, W_ho, W_hc   [H][H] row-major
    const float* bias[4]; // b_i, b_f, b_o, b_c       [H]
    float* Y;             // [B][T][H]
    float* hbuf;          // ws: 2 * B * H floats (double buffer)
    unsigned int* ctr;    // ws: NGROUP counters, 64-uint padded
};

__device__ __forceinline__ float fast_sigmoid(float x) {
    return 1.0f / (1.0f + __expf(-x));
}

__device__ __forceinline__ float fast_tanh(float x) {
    float ax = fabsf(x);
    float e  = __expf(-2.0f * ax);
    float r  = (1.0f - e) / (1.0f + e);
    return copysignf(r, x);
}

// hbuf/ctr are accessed ONLY via cache-bypassing (agent-scope relaxed) ops in
// the main kernel, so the init writes must also be write-through.
__global__ void init_ws(float* hbuf, unsigned int* ctr) {
    int i = blockIdx.x * blockDim.x + threadIdx.x;
    int stride = gridDim.x * blockDim.x;
    for (int k = i; k < 2 * BSZ * HH; k += stride)
        __hip_atomic_store(&hbuf[k], 0.0f, __ATOMIC_RELAXED, __HIP_MEMORY_SCOPE_AGENT);
    if (i < 8 * 64)
        __hip_atomic_store(&ctr[i], 0u, __ATOMIC_RELAXED, __HIP_MEMORY_SCOPE_AGENT);
}

// Persistent LSTM. 256 blocks x 1024 threads. 99.3 KB LDS -> 1 block/CU,
// 16 waves = 4 waves/SIMD.
//
// LAUNCH_BOUNDS HISTORY (R3 disaster): __launch_bounds__(1024,4) resolved to
// a 64-VGPR cap on this compiler (VGPR_Count=64, WRITE_SIZE 135MB->74.8GB of
// scratch spill, 9x slower). (NT,1) lets the backend apply only the
// launchability cap for a 1024-thread block (128 VGPR); kernel needs ~88-100.
// If VGPR_Count reads 64 or WRITE_SIZE >> 135 MB again: it spilled.
//
// SPILL GUARD: 32 w-floats/thread total; both FMA loops are 4-chunk unrolled
// with sched_barrier(0) after each chunk (<=16 b128 loads in flight) — the
// exact pattern that compiled to 88 VGPR in R2.
//
// CELL-UPDATE BANK FIX (R3 counter: 3.35e7 conflicts): reads at
// (bbu*16+ss)*33 have bank = 16*(bbu&1)+ss+8g+jju -> 4-way when all lanes
// share ss. Rotating ss per thread by 4*(bbu>>1) spreads the four colliding
// bbu values across 4 banks -> only free 2-way aliasing remains. Sum order
// change = rounding only.
//
// XCD-pair swizzle: group g -> XCDs {2g,2g+1} (bid%8 round-robin assumption).
// COHERENCE: h exchange is Infinity-Cache-coherent with ZERO fences.
// Producer: relaxed agent store (write-through). __syncthreads drains vmcnt.
// tid0 relaxed fetch_add publish; consumer tid0 relaxed spin, h staged via
// relaxed agent loads (bypass L1/L2, served by IF).
__global__ __launch_bounds__(NT, 1) void lstm_persist(Params p) {
    __shared__ float hs[GBATCH * HH];         // 32 KB: h_{t-1}, 16 batches
    __shared__ float xs[GBATCH * DD];         // 32 KB: x_t, 16 batches
    __shared__ float part[GBATCH * 16 * 33];  // 33.8 KB: partials [bb][spair][33(c)]

    const int bid  = blockIdx.x;
    // XCD-pair swizzle (XCD assumed = bid & 7)
    const int g    = (bid & 7) >> 1;               // group 0..3 -> XCDs {2g,2g+1}
    const int k    = ((bid >> 3) << 1) | (bid & 1); // block-in-group 0..63
    const int tid  = threadIdx.x;
    const int c    = tid & 31;             // col 0..31
    const int s    = tid >> 5;             // K-slice 0..31
    const int gate = c >> 3;
    const int jcol = k * 8 + (c & 7);      // weight-matrix column
    const int b0   = g * GBATCH;
    const int kb   = s * 16;               // K-slice start (16 rows/thread)

    // ---- one-time: W_x and W_h slices into registers (16+16 floats) ----
    const float* WxG = p.Wx[gate];
    const float* WhG = p.Wh[gate];
    float4 wx4[4], wh4[4];
#pragma unroll
    for (int i = 0; i < 4; ++i) {
        int kk = kb + i * 4;
        wx4[i] = make_float4(WxG[(kk + 0) * HH + jcol], WxG[(kk + 1) * HH + jcol],
                             WxG[(kk + 2) * HH + jcol], WxG[(kk + 3) * HH + jcol]);
        wh4[i] = make_float4(WhG[(kk + 0) * HH + jcol], WhG[(kk + 1) * HH + jcol],
                             WhG[(kk + 2) * HH + jcol], WhG[(kk + 3) * HH + jcol]);
    }

    // Cell-update thread state (threads 0..127): (batch bbu, unit jju)
    const int bbu = tid >> 3;              // 0..15 (for tid<128)
    const int jju = tid & 7;
    const int ju  = k * 8 + jju;
    float cst = 0.0f;
    float bI = 0.f, bF = 0.f, bO = 0.f, bC = 0.f;
    if (tid < 128) {
        bI = p.bias[0][ju];
        bF = p.bias[1][ju];
        bO = p.bias[2][ju];
        bC = p.bias[3][ju];
    }

    unsigned int* ctrp = p.ctr + g * 64;
    const float4* xsrc = (const float4*)p.X;
    float4* hs4 = (float4*)hs;
    float4* xs4 = (float4*)xs;

    for (int t = 0; t < TT; ++t) {
        // ---- 1. stage x_t (no cross-block dependency): 2 float4/thread ----
#pragma unroll
        for (int u = 0; u < 2; ++u) {
            int idx = tid + u * NT;            // 0..2047 (float4 index)
            int b   = idx >> 7;                // 0..15
            int dd  = idx & 127;               // float4 within row
            xs4[b * 128 + dd] = xsrc[((size_t)(b0 + b) * TT + t) * 128 + dd];
        }
        __syncthreads();

        // ---- 2. x-projection FMAs, weights from registers.
        //      4 chunks x (16 ds_read_b128 + 64 FMA), sched_barrier bounded ----
        float acc[16];
#pragma unroll
        for (int bb = 0; bb < 16; ++bb) acc[bb] = 0.0f;
#pragma unroll
        for (int i4 = 0; i4 < 4; ++i4) {
            const float4 w = wx4[i4];
            const float4* xp = &xs4[s * 4 + i4];
#pragma unroll
            for (int bb = 0; bb < 16; ++bb) {
                float4 xv = xp[bb * 128];      // half-wave broadcast
                float a = acc[bb];
                a = fmaf(xv.x, w.x, a);
                a = fmaf(xv.y, w.y, a);
                a = fmaf(xv.z, w.z, a);
                a = fmaf(xv.w, w.w, a);
                acc[bb] = a;
            }
            __builtin_amdgcn_sched_barrier(0);
        }

        // ---- 3. wait for h_{t-1}: tid0-only relaxed spin (bypass load reads
        //      the IF directly — no fence, no cache invalidation) ----
        if (tid == 0) {
            const unsigned int need = (unsigned int)(GBLK * t);
            while (__hip_atomic_load(ctrp, __ATOMIC_RELAXED, __HIP_MEMORY_SCOPE_AGENT) < need) {
                __builtin_amdgcn_s_sleep(2);
            }
        }
        __syncthreads();

        // ---- 4. stage h_{t-1}: cache-bypassing (IF-coherent) loads,
        //      register-batched so all 8 loads are in flight at once ----
        {
            const float* hsrc = p.hbuf + (size_t)(t & 1) * BSZ * HH;
            float tmp[8];
#pragma unroll
            for (int u = 0; u < 8; ++u) {
                int idx = tid + u * NT;        // 0..8191
                int b   = idx >> 9;            // 0..15
                int d   = idx & 511;
                tmp[u] = __hip_atomic_load(&hsrc[(size_t)(b0 + b) * HH + d],
                                           __ATOMIC_RELAXED, __HIP_MEMORY_SCOPE_AGENT);
            }
#pragma unroll
            for (int u = 0; u < 8; ++u) {
                int idx = tid + u * NT;
                hs[idx] = tmp[u];
            }
        }
        __syncthreads();

        // ---- 5. recurrent FMAs, weights from registers ----
#pragma unroll
        for (int i4 = 0; i4 < 4; ++i4) {
            const float4 w = wh4[i4];
            const float4* hp = &hs4[s * 4 + i4];
#pragma unroll
            for (int bb = 0; bb < 16; ++bb) {
                float4 hv = hp[bb * 128];      // half-wave broadcast
                float a = acc[bb];
                a = fmaf(hv.x, w.x, a);
                a = fmaf(hv.y, w.y, a);
                a = fmaf(hv.z, w.z, a);
                a = fmaf(hv.w, w.w, a);
                acc[bb] = a;
            }
            __builtin_amdgcn_sched_barrier(0);
        }

        // ---- 6. pair-combine K-slices s and s^1 in-register (same wave:
        //      lanes 0..31 hold s even, 32..63 hold s odd), then write 16
        //      partial slices (stride 33: conflict-free) ----
#pragma unroll
        for (int bb = 0; bb < 16; ++bb)
            acc[bb] += __shfl_xor(acc[bb], 32);
        if ((s & 1) == 0) {
#pragma unroll
            for (int bb = 0; bb < 16; ++bb)
                part[(bb * 16 + (s >> 1)) * 33 + c] = acc[bb];
        }
        __syncthreads();

        // ---- 7. cell update (ss order rotated per thread: bank-spread) ----
        if (tid < 128) {
            float v0 = bI, v1 = bF, v2 = bO, v3 = bC;
            const int q4 = ((bbu >> 1) & 3) << 2;   // {0,4,8,12}
#pragma unroll
            for (int i = 0; i < 16; ++i) {
                int ss = (i + q4) & 15;
                const float* pr = &part[(bbu * 16 + ss) * 33];
                v0 += pr[0 * 8 + jju];
                v1 += pr[1 * 8 + jju];
                v2 += pr[2 * 8 + jju];
                v3 += pr[3 * 8 + jju];
            }
            float I  = fast_sigmoid(v0);
            float F  = fast_sigmoid(v1);
            float O  = fast_sigmoid(v2);
            float Cd = fast_tanh(v3);
            cst = fmaf(F, cst, I * Cd);
            float h = O * fast_tanh(cst);
            // write-through to the IF (coherence point)
            __hip_atomic_store(&p.hbuf[(size_t)((t + 1) & 1) * BSZ * HH + (b0 + bbu) * HH + ju],
                               h, __ATOMIC_RELAXED, __HIP_MEMORY_SCOPE_AGENT);
            p.Y[((size_t)(b0 + bbu) * TT + t) * HH + ju] = h;
        }
        __syncthreads();   // drains vmcnt: h stores complete at the IF

        // ---- 8. publish: tid0 RELAXED add (ordering via the vmcnt drain) ----
        if (tid == 0) {
            __hip_atomic_fetch_add(ctrp, 1u, __ATOMIC_RELAXED, __HIP_MEMORY_SCOPE_AGENT);
        }
    }
}

extern "C" void kernel_launch(void* const* d_in, const int* in_sizes, int n_in,
                              void* d_out, int out_size, void* d_ws, size_t ws_size,
                              hipStream_t stream) {
    Params p;
    p.X       = (const float*)d_in[0];
    p.Wx[0]   = (const float*)d_in[1];
    p.Wh[0]   = (const float*)d_in[2];
    p.bias[0] = (const float*)d_in[3];
    p.Wx[1]   = (const float*)d_in[4];
    p.Wh[1]   = (const float*)d_in[5];
    p.bias[1] = (const float*)d_in[6];
    p.Wx[2]   = (const float*)d_in[7];
    p.Wh[2]   = (const float*)d_in[8];
    p.bias[2] = (const float*)d_in[9];
    p.Wx[3]   = (const float*)d_in[10];
    p.Wh[3]   = (const float*)d_in[11];
    p.bias[3] = (const float*)d_in[12];
    p.Y       = (float*)d_out;
    p.hbuf    = (float*)d_ws;
    p.ctr     = (unsigned int*)((char*)d_ws + (size_t)2 * BSZ * HH * sizeof(float));

    // ws is poisoned 0xAA before every timed launch: zero h0 double-buffer + counters
    init_ws<<<64, 256, 0, stream>>>(p.hbuf, p.ctr);

    lstm_persist<<<dim3(256), dim3(NT), 0, stream>>>(p);
}

// Round 6
// 3506.468 us; speedup vs baseline: 10.8713x; 10.1425x over previous
//
#include <hip/hip_runtime.h>

#define TT 512
#define BSZ 64
#define DD 512
#define HH 512
#define NGROUP 4
#define GBLK 64        // blocks per group
#define GBATCH 16      // batches per group
#define NT 512         // threads per block

// part layout strides (floats), engineered conflict-free:
//  write lanes (4 sp x 2 par x 8 u): bank = (8sp + 16par + 8gi + u) % 32 -> 2-way (free)
//  cell lanes (16 bbu x 8 jju):      bank = (4bbu + jju + C) % 32       -> 2-way (free)
#define PART_SP 40
#define PART_BB 1284   // >= 32*40, and PART_BB % 32 == 4

struct Params {
    const float* X;
    const float* Wx[4];   // W_xi, W_xf, W_xo, W_xc   [D][H] row-major
    const float* Wh[4];   // W_hi, W_hf, W_ho, W_hc   [H][H] row-major
    const float* bias[4]; // b_i, b_f, b_o, b_c       [H]
    float* Y;             // [B][T][H]
    float* hbuf;          // ws: 2 * B * H floats (double buffer)
    unsigned int* ctr;    // ws: NGROUP counters, 64-uint padded
};

__device__ __forceinline__ float fast_sigmoid(float x) {
    return 1.0f / (1.0f + __expf(-x));
}

__device__ __forceinline__ float fast_tanh(float x) {
    float ax = fabsf(x);
    float e  = __expf(-2.0f * ax);
    float r  = (1.0f - e) / (1.0f + e);
    return copysignf(r, x);
}

// xor-8 pair-sum on the VALU pipe via DPP row_ror:8 (lane l <-> l^8 within each
// 16-lane row). MUST stay off the LDS pipe: a ds_swizzle-based __shfl_xor here
// would add 512 LDS wave-instrs/CU/step and erase the fan-out win.
__device__ __forceinline__ float dpp_xor8_add(float v) {
    int pv = __builtin_amdgcn_update_dpp(0, __float_as_int(v),
                                         0x128 /*row_ror:8*/, 0xf, 0xf, true);
    return v + __int_as_float(pv);
}

// hbuf/ctr are accessed ONLY via cache-bypassing (agent-scope relaxed) ops in
// the main kernel, so the init writes must also be write-through.
__global__ void init_ws(float* hbuf, unsigned int* ctr) {
    int i = blockIdx.x * blockDim.x + threadIdx.x;
    int stride = gridDim.x * blockDim.x;
    for (int k = i; k < 2 * BSZ * HH; k += stride)
        __hip_atomic_store(&hbuf[k], 0.0f, __ATOMIC_RELAXED, __HIP_MEMORY_SCOPE_AGENT);
    if (i < 8 * 64)
        __hip_atomic_store(&ctr[i], 0u, __ATOMIC_RELAXED, __HIP_MEMORY_SCOPE_AGENT);
}

// Persistent LSTM, R6: FAN-OUT restructure on the PROVEN residency topology.
// 256 blocks x 512 threads, 144.3 KB LDS -> 1 block/CU (no co-residency
// requirement beyond R2's; R5's 2-blocks/CU design deadlocked the container).
//
// WHY: R2 (4287us) was LDS-INSTRUCTION-pipe bound: ~2300 LDS wave-instrs/CU/step
// x ~11cyc ~= 9.6us ~= the measured 9.0us step. Each ds_read_b128 broadcast fed
// only 4 FMAs (1 column/thread). This version: thread owns 4 columns (one per
// gate, same unit) -> 16 FMAs per b128 read -> 512 b128/CU/step (~2.6us).
//
// Partition: 4 groups x 64 blocks (XCD-pair swizzle: group g -> XCDs {2g,2g+1}).
// Block k owns units [8k,8k+8). Thread (u=tid&7, s=tid>>3): unit u, ALL 4
// gates, K-slice [8s,8s+8). Weights in regs: wx4[4][2]+wh4[4][2] = 64 floats.
// acc[4][16] (4 gates x 16 batches) = 64. Est ~160 VGPR: fine for 2 waves/SIMD
// (cliff at 256); NT=512 allocation was sane in R2 (88, no cap pathology).
// SPILL TRIPWIRE: VGPR_Count=64 or WRITE_SIZE >> 135 MB.
//
// Slice reduce: DPP xor8 pair-sum (VALU pipe), then s-even threads write gates
// {0,1}, s-odd write gates {2,3} -> 32 sp-slices in part; cell update sums 32.
// All acc[] indices compile-time constant (runtime-indexed reg arrays -> scratch).
//
// COHERENCE (unchanged, proven): h exchange is IF-coherent, ZERO fences.
// Producer: relaxed agent store (write-through). __syncthreads drains vmcnt.
// tid0 relaxed fetch_add publish; consumer tid0 relaxed spin; h staged via
// relaxed agent u64 loads (bypass L1/L2, served by IF).
__global__ __launch_bounds__(NT, 1) void lstm_persist(Params p) {
    __shared__ float xs[GBATCH * DD];        // 32 KB: x_t, 16 batches
    __shared__ float hs[GBATCH * HH];        // 32 KB: h_{t-1}, 16 batches
    __shared__ float part[16 * PART_BB];     // 80.25 KB: partials

    const int bid  = blockIdx.x;
    // XCD-pair swizzle (XCD assumed = bid & 7)
    const int g    = (bid & 7) >> 1;               // group 0..3 -> XCDs {2g,2g+1}
    const int k    = ((bid >> 3) << 1) | (bid & 1); // block-in-group 0..63
    const int tid  = threadIdx.x;
    const int u    = tid & 7;              // unit-in-block 0..7
    const int s    = tid >> 3;             // K-slice 0..63
    const int kb   = s * 8;                // K start (8 rows/thread)
    const int jc   = k * 8 + u;            // column in each gate's weight matrix
    const int b0   = g * GBATCH;

    // ---- one-time: weights into registers (4 gates x 8 k, x and h) ----
    float4 wx4[4][2], wh4[4][2];
#pragma unroll
    for (int g4 = 0; g4 < 4; ++g4) {
        const float* WxG = p.Wx[g4];
        const float* WhG = p.Wh[g4];
#pragma unroll
        for (int k4 = 0; k4 < 2; ++k4) {
            int kk = kb + k4 * 4;
            wx4[g4][k4] = make_float4(WxG[(kk + 0) * HH + jc], WxG[(kk + 1) * HH + jc],
                                      WxG[(kk + 2) * HH + jc], WxG[(kk + 3) * HH + jc]);
            wh4[g4][k4] = make_float4(WhG[(kk + 0) * HH + jc], WhG[(kk + 1) * HH + jc],
                                      WhG[(kk + 2) * HH + jc], WhG[(kk + 3) * HH + jc]);
        }
    }

    // Cell-update thread state (threads 0..127): (batch bbu, unit jju)
    const int bbu = tid >> 3;              // 0..15 (for tid<128)
    const int jju = tid & 7;
    const int ju  = k * 8 + jju;
    float cst = 0.0f;
    float bI = 0.f, bF = 0.f, bO = 0.f, bC = 0.f;
    if (tid < 128) {
        bI = p.bias[0][ju];
        bF = p.bias[1][ju];
        bO = p.bias[2][ju];
        bC = p.bias[3][ju];
    }

    unsigned int* ctrp = p.ctr + g * 64;
    const float4* xsrc = (const float4*)p.X;
    float4* xs4 = (float4*)xs;
    float4* hs4 = (float4*)hs;

#define ACC4(A, V, W) \
    A = fmaf((V).x, (W).x, A); A = fmaf((V).y, (W).y, A); \
    A = fmaf((V).z, (W).z, A); A = fmaf((V).w, (W).w, A);

    for (int t = 0; t < TT; ++t) {
        // ---- 1. stage x_t (no cross-block dependency): 4 float4/thread ----
#pragma unroll
        for (int uu = 0; uu < 4; ++uu) {
            int idx = tid + uu * NT;           // 0..2047 (float4 index)
            int b   = idx >> 7;                // 0..15
            int dd  = idx & 127;               // float4 within row
            xs4[b * 128 + dd] = xsrc[((size_t)(b0 + b) * TT + t) * 128 + dd];
        }
        __syncthreads();

        // ---- 2. x-projection: each b128 broadcast feeds 16 FMAs ----
        float acc[4][16];
#pragma unroll
        for (int g4 = 0; g4 < 4; ++g4)
#pragma unroll
            for (int bb = 0; bb < 16; ++bb) acc[g4][bb] = 0.0f;
#pragma unroll
        for (int k4 = 0; k4 < 2; ++k4) {
#pragma unroll
            for (int bb = 0; bb < 16; ++bb) {
                float4 xv = xs4[bb * 128 + s * 2 + k4];   // 8-lane broadcast
                ACC4(acc[0][bb], xv, wx4[0][k4]);
                ACC4(acc[1][bb], xv, wx4[1][k4]);
                ACC4(acc[2][bb], xv, wx4[2][k4]);
                ACC4(acc[3][bb], xv, wx4[3][k4]);
                if ((bb & 3) == 3) __builtin_amdgcn_sched_barrier(0);
            }
        }

        // ---- 3. wait for h_{t-1}: tid0-only relaxed spin (IF read, no fence) ----
        if (tid == 0) {
            const unsigned int need = (unsigned int)(GBLK * t);
            while (__hip_atomic_load(ctrp, __ATOMIC_RELAXED, __HIP_MEMORY_SCOPE_AGENT) < need) {
                __builtin_amdgcn_s_sleep(2);
            }
        }
        __syncthreads();

        // ---- 4. stage h_{t-1}: u64 cache-bypassing loads, 8 in flight ----
        {
            const unsigned long long* hsrc =
                (const unsigned long long*)(p.hbuf + (size_t)(t & 1) * BSZ * HH);
            unsigned long long tmpu[8];
#pragma unroll
            for (int uu = 0; uu < 8; ++uu) {
                int idx = tid + uu * NT;       // 0..4095 (u64 index)
                int b   = idx >> 8;            // 0..15
                int d   = idx & 255;
                tmpu[uu] = __hip_atomic_load(&hsrc[(size_t)(b0 + b) * 256 + d],
                                             __ATOMIC_RELAXED, __HIP_MEMORY_SCOPE_AGENT);
            }
            unsigned long long* hsu = (unsigned long long*)hs;
#pragma unroll
            for (int uu = 0; uu < 8; ++uu)
                hsu[tid + uu * NT] = tmpu[uu];
        }
        __syncthreads();

        // ---- 5. recurrent FMAs ----
#pragma unroll
        for (int k4 = 0; k4 < 2; ++k4) {
#pragma unroll
            for (int bb = 0; bb < 16; ++bb) {
                float4 hv = hs4[bb * 128 + s * 2 + k4];   // 8-lane broadcast
                ACC4(acc[0][bb], hv, wh4[0][k4]);
                ACC4(acc[1][bb], hv, wh4[1][k4]);
                ACC4(acc[2][bb], hv, wh4[2][k4]);
                ACC4(acc[3][bb], hv, wh4[3][k4]);
                if ((bb & 3) == 3) __builtin_amdgcn_sched_barrier(0);
            }
        }

        // ---- 6. DPP xor8 pair-sum (VALU), then write 32 sp-slices.
        //      s even -> gates {0,1} (cols 0..15); s odd -> {2,3} (16..31).
        //      acc indices static on both branches (no runtime reg indexing).
#pragma unroll
        for (int g4 = 0; g4 < 4; ++g4)
#pragma unroll
            for (int bb = 0; bb < 16; ++bb)
                acc[g4][bb] = dpp_xor8_add(acc[g4][bb]);
        {
            const int sp = s >> 1;             // 0..31
            float* dst = &part[sp * PART_SP + (s & 1) * 16 + u];
            if ((s & 1) == 0) {
#pragma unroll
                for (int bb = 0; bb < 16; ++bb) {
                    dst[bb * PART_BB + 0] = acc[0][bb];
                    dst[bb * PART_BB + 8] = acc[1][bb];
                }
            } else {
#pragma unroll
                for (int bb = 0; bb < 16; ++bb) {
                    dst[bb * PART_BB + 0] = acc[2][bb];
                    dst[bb * PART_BB + 8] = acc[3][bb];
                }
            }
        }
        __syncthreads();

        // ---- 7. cell update (2 waves: 16 batches x 8 units) ----
        if (tid < 128) {
            float v0 = bI, v1 = bF, v2 = bO, v3 = bC;
            const float* pr = &part[bbu * PART_BB + jju];
#pragma unroll
            for (int ss = 0; ss < 32; ++ss) {
                v0 += pr[ss * PART_SP + 0];
                v1 += pr[ss * PART_SP + 8];
                v2 += pr[ss * PART_SP + 16];
                v3 += pr[ss * PART_SP + 24];
            }
            float I  = fast_sigmoid(v0);
            float F  = fast_sigmoid(v1);
            float O  = fast_sigmoid(v2);
            float Cd = fast_tanh(v3);
            cst = fmaf(F, cst, I * Cd);
            float h = O * fast_tanh(cst);
            // write-through to the IF (coherence point)
            __hip_atomic_store(&p.hbuf[(size_t)((t + 1) & 1) * BSZ * HH + (b0 + bbu) * HH + ju],
                               h, __ATOMIC_RELAXED, __HIP_MEMORY_SCOPE_AGENT);
            p.Y[((size_t)(b0 + bbu) * TT + t) * HH + ju] = h;
        }
        __syncthreads();   // drains vmcnt: h stores complete at the IF

        // ---- 8. publish: tid0 RELAXED add (ordering via the vmcnt drain) ----
        if (tid == 0) {
            __hip_atomic_fetch_add(ctrp, 1u, __ATOMIC_RELAXED, __HIP_MEMORY_SCOPE_AGENT);
        }
    }
#undef ACC4
}

extern "C" void kernel_launch(void* const* d_in, const int* in_sizes, int n_in,
                              void* d_out, int out_size, void* d_ws, size_t ws_size,
                              hipStream_t stream) {
    Params p;
    p.X       = (const float*)d_in[0];
    p.Wx[0]   = (const float*)d_in[1];
    p.Wh[0]   = (const float*)d_in[2];
    p.bias[0] = (const float*)d_in[3];
    p.Wx[1]   = (const float*)d_in[4];
    p.Wh[1]   = (const float*)d_in[5];
    p.bias[1] = (const float*)d_in[6];
    p.Wx[2]   = (const float*)d_in[7];
    p.Wh[2]   = (const float*)d_in[8];
    p.bias[2] = (const float*)d_in[9];
    p.Wx[3]   = (const float*)d_in[10];
    p.Wh[3]   = (const float*)d_in[11];
    p.bias[3] = (const float*)d_in[12];
    p.Y       = (float*)d_out;
    p.hbuf    = (float*)d_ws;
    p.ctr     = (unsigned int*)((char*)d_ws + (size_t)2 * BSZ * HH * sizeof(float));

    // ws is poisoned 0xAA before every timed launch: zero h0 double-buffer + counters
    init_ws<<<64, 256, 0, stream>>>(p.hbuf, p.ctr);

    lstm_persist<<<dim3(256), dim3(NT), 0, stream>>>(p);
}